// Round 1
// baseline (304.783 us; speedup 1.0000x reference)
//
#include <hip/hip_runtime.h>
#include <hip/hip_bf16.h>
#include <cstddef>

// Problem dims
#define BATCH 128
#define T1 4096
#define P1 2048
#define T2 2048
#define P2 1024
#define NNODE 1024

// Workspace layout (bytes). h1 region is reused for Pf/Pg after conv2 consumed h1.
#define OFF_H1   ((size_t)0)
#define OFF_PF   ((size_t)0)
#define OFF_PG   ((size_t)16777216)
#define OFF_H2   ((size_t)33554432)
#define OFF_HW   ((size_t)67108864)
#define OFF_SSRC ((size_t)75497472)
#define OFF_SDST ((size_t)76021760)
#define OFF_POOL ((size_t)76546048)
#define OFF_SK   ((size_t)76554240)
// total required ws: 77,078,528 bytes

// ---------------------------------------------------------------------------
// conv1 (17 -> 32, k=5, pad=2) + relu + maxpool2.  x:[128,17,4096] -> h1:[128,32,2048]
// Block: 256 threads = 256 pooled positions. Grid: (2048/256, 128).
__global__ __launch_bounds__(256) void conv1_kernel(
    const float* __restrict__ x, const float* __restrict__ w,
    const float* __restrict__ bias, float* __restrict__ out)
{
    __shared__ __align__(16) float sx[17][516];
    __shared__ __align__(16) float sw[17][5][32];
    const int tid = threadIdx.x;
    const int b = blockIdx.y;
    const int p0 = blockIdx.x * 256;

    for (int idx = tid; idx < 17 * 5 * 32; idx += 256) {
        int o = idx & 31, rest = idx >> 5;
        int k = rest % 5, c = rest / 5;
        sw[c][k][o] = w[(o * 17 + c) * 5 + k];
    }
    const float* xb = x + (size_t)b * (17 * T1);
    const int tstart = 2 * p0 - 2;
    for (int idx = tid; idx < 17 * 516; idx += 256) {
        int c = idx / 516, tt = idx - c * 516;
        int t = tstart + tt;
        sx[c][tt] = (t >= 0 && t < T1) ? xb[c * T1 + t] : 0.0f;
    }
    __syncthreads();

    const int p = tid;
    float4 acc0[8], acc1[8];
    const float4* bv = (const float4*)bias;
#pragma unroll
    for (int q = 0; q < 8; q++) { acc0[q] = bv[q]; acc1[q] = bv[q]; }

    for (int c = 0; c < 17; c++) {
        float xv[6];
#pragma unroll
        for (int kk = 0; kk < 6; kk++) xv[kk] = sx[c][2 * p + kk];
#pragma unroll
        for (int k = 0; k < 5; k++) {
            const float4* wq = (const float4*)(&sw[c][k][0]);
            float x0 = xv[k], x1 = xv[k + 1];
#pragma unroll
            for (int q = 0; q < 8; q++) {
                float4 wv = wq[q];
                acc0[q].x += x0 * wv.x; acc0[q].y += x0 * wv.y;
                acc0[q].z += x0 * wv.z; acc0[q].w += x0 * wv.w;
                acc1[q].x += x1 * wv.x; acc1[q].y += x1 * wv.y;
                acc1[q].z += x1 * wv.z; acc1[q].w += x1 * wv.w;
            }
        }
    }
    float* ob = out + (size_t)b * (32 * P1) + p0 + p;
#pragma unroll
    for (int q = 0; q < 8; q++) {
        float4 a0 = acc0[q], a1 = acc1[q];
        ob[(size_t)(4 * q + 0) * P1] = fmaxf(fmaxf(a0.x, a1.x), 0.0f);
        ob[(size_t)(4 * q + 1) * P1] = fmaxf(fmaxf(a0.y, a1.y), 0.0f);
        ob[(size_t)(4 * q + 2) * P1] = fmaxf(fmaxf(a0.z, a1.z), 0.0f);
        ob[(size_t)(4 * q + 3) * P1] = fmaxf(fmaxf(a0.w, a1.w), 0.0f);
    }
}

// ---------------------------------------------------------------------------
// conv2 (32 -> 64, k=5, pad=2) + relu + maxpool2. h1:[128,32,2048] -> h2:[128,64,1024]
// Block: 256 threads = 128 pooled positions x 2 channel-halves. Grid: (1024/128, 128).
__global__ __launch_bounds__(256) void conv2_kernel(
    const float* __restrict__ h1, const float* __restrict__ w,
    const float* __restrict__ bias, float* __restrict__ out)
{
    __shared__ __align__(16) float sx[32][260];
    __shared__ __align__(16) float sw[32][5][64];
    const int tid = threadIdx.x;
    const int b = blockIdx.y;
    const int p0 = blockIdx.x * 128;
    const int p = tid & 127;
    const int oh = tid >> 7;   // 0/1 -> output channels [oh*32, oh*32+32)

    for (int idx = tid; idx < 64 * 32 * 5; idx += 256) {
        int o = idx & 63, rest = idx >> 6;
        int k = rest % 5, c = rest / 5;
        sw[c][k][o] = w[(o * 32 + c) * 5 + k];
    }
    const float* xb = h1 + (size_t)b * (32 * T2);
    const int tstart = 2 * p0 - 2;
    for (int idx = tid; idx < 32 * 260; idx += 256) {
        int c = idx / 260, tt = idx - c * 260;
        int t = tstart + tt;
        sx[c][tt] = (t >= 0 && t < T2) ? xb[c * T2 + t] : 0.0f;
    }
    __syncthreads();

    float4 acc0[8], acc1[8];
    const float4* bv = (const float4*)(bias + oh * 32);
#pragma unroll
    for (int q = 0; q < 8; q++) { acc0[q] = bv[q]; acc1[q] = bv[q]; }

    for (int c = 0; c < 32; c++) {
        float xv[6];
#pragma unroll
        for (int kk = 0; kk < 6; kk++) xv[kk] = sx[c][2 * p + kk];
#pragma unroll
        for (int k = 0; k < 5; k++) {
            const float4* wq = (const float4*)(&sw[c][k][oh * 32]);
            float x0 = xv[k], x1 = xv[k + 1];
#pragma unroll
            for (int q = 0; q < 8; q++) {
                float4 wv = wq[q];
                acc0[q].x += x0 * wv.x; acc0[q].y += x0 * wv.y;
                acc0[q].z += x0 * wv.z; acc0[q].w += x0 * wv.w;
                acc1[q].x += x1 * wv.x; acc1[q].y += x1 * wv.y;
                acc1[q].z += x1 * wv.z; acc1[q].w += x1 * wv.w;
            }
        }
    }
    float* ob = out + (size_t)b * (64 * P2) + (size_t)(oh * 32) * P2 + p0 + p;
#pragma unroll
    for (int q = 0; q < 8; q++) {
        float4 a0 = acc0[q], a1 = acc1[q];
        ob[(size_t)(4 * q + 0) * P2] = fmaxf(fmaxf(a0.x, a1.x), 0.0f);
        ob[(size_t)(4 * q + 1) * P2] = fmaxf(fmaxf(a0.y, a1.y), 0.0f);
        ob[(size_t)(4 * q + 2) * P2] = fmaxf(fmaxf(a0.z, a1.z), 0.0f);
        ob[(size_t)(4 * q + 3) * P2] = fmaxf(fmaxf(a0.w, a1.w), 0.0f);
    }
}

// ---------------------------------------------------------------------------
// GAT projection: hw[b,n,o] = sum_d h2[b,d,n]*gat_w[o,d]; s_src/s_dst dots.
__global__ __launch_bounds__(256) void gat_hw_kernel(
    const float* __restrict__ h2, const float* __restrict__ gat_w,
    const float* __restrict__ att_src, const float* __restrict__ att_dst,
    float* __restrict__ hw, float* __restrict__ s_src, float* __restrict__ s_dst)
{
    __shared__ __align__(16) float sgw[64][16];
    __shared__ float sas[16], sad[16];
    const int tid = threadIdx.x, b = blockIdx.y;
    const int n = blockIdx.x * 256 + tid;
    for (int idx = tid; idx < 1024; idx += 256) {
        int o = idx & 15, d = idx >> 4;
        sgw[d][o] = gat_w[o * 64 + d];
    }
    if (tid < 16) { sas[tid] = att_src[tid]; sad[tid] = att_dst[tid]; }
    __syncthreads();

    const float* hb = h2 + (size_t)b * (64 * NNODE) + n;
    float4 acc[4];
#pragma unroll
    for (int q = 0; q < 4; q++) acc[q] = make_float4(0.f, 0.f, 0.f, 0.f);
    for (int d = 0; d < 64; d++) {
        float hv = hb[(size_t)d * NNODE];
        const float4* wq = (const float4*)(&sgw[d][0]);
#pragma unroll
        for (int q = 0; q < 4; q++) {
            float4 wv = wq[q];
            acc[q].x += hv * wv.x; acc[q].y += hv * wv.y;
            acc[q].z += hv * wv.z; acc[q].w += hv * wv.w;
        }
    }
    float* af = (float*)acc;
    float ssrc = 0.f, sdst = 0.f;
#pragma unroll
    for (int c = 0; c < 16; c++) { ssrc += af[c] * sas[c]; sdst += af[c] * sad[c]; }
    float4* hwp = (float4*)(hw + ((size_t)b * NNODE + n) * 16);
#pragma unroll
    for (int q = 0; q < 4; q++) hwp[q] = acc[q];
    s_src[b * NNODE + n] = ssrc;
    s_dst[b * NNODE + n] = sdst;
}

// ---------------------------------------------------------------------------
__device__ __forceinline__ void accum17(float* L, float wgt, const float4* hj)
{
    float4 h0 = hj[0], h1 = hj[1], h2 = hj[2], h3 = hj[3];
    L[0]  += wgt * h0.x; L[1]  += wgt * h0.y; L[2]  += wgt * h0.z; L[3]  += wgt * h0.w;
    L[4]  += wgt * h1.x; L[5]  += wgt * h1.y; L[6]  += wgt * h1.z; L[7]  += wgt * h1.w;
    L[8]  += wgt * h2.x; L[9]  += wgt * h2.y; L[10] += wgt * h2.z; L[11] += wgt * h2.w;
    L[12] += wgt * h3.x; L[13] += wgt * h3.y; L[14] += wgt * h3.z; L[15] += wgt * h3.w;
    L[16] += wgt;
}

__device__ __forceinline__ void store17(float* dst, const float* L)
{
    *(float4*)(dst + 0)  = make_float4(L[0],  L[1],  L[2],  L[3]);
    *(float4*)(dst + 4)  = make_float4(L[4],  L[5],  L[6],  L[7]);
    *(float4*)(dst + 8)  = make_float4(L[8],  L[9],  L[10], L[11]);
    *(float4*)(dst + 12) = make_float4(L[12], L[13], L[14], L[15]);
    dst[16] = L[16];
}

// Per-batch: bitonic sort s_src (with index payload), then exclusive prefix sums
// of f = exp(ss-M)*[hw,1] and g = exp(0.2*(ss-M))*[hw,1] over sorted order.
// Rows padded to 20 floats. Row t = sum over sorted positions u < t; row 1024 = totals.
__global__ __launch_bounds__(256) void attn_prefix_kernel(
    const float* __restrict__ s_src, const float* __restrict__ hw,
    float* __restrict__ Pf, float* __restrict__ Pg, float* __restrict__ skeys)
{
    __shared__ float skey[1024];
    __shared__ int   sidx[1024];
    __shared__ float wsum[4][34];
    const int tid = threadIdx.x, b = blockIdx.x;

    const float* ssb = s_src + b * NNODE;
    for (int t = tid; t < 1024; t += 256) { skey[t] = ssb[t]; sidx[t] = t; }
    __syncthreads();

    // bitonic sort ascending (1024 = 2^10); 512 disjoint pairs per stage.
    for (int k = 2; k <= 1024; k <<= 1) {
        for (int j = k >> 1; j > 0; j >>= 1) {
#pragma unroll
            for (int rep = 0; rep < 2; rep++) {
                int t = tid + rep * 256;
                int idx = ((t & ~(j - 1)) << 1) | (t & (j - 1));
                int ixj = idx | j;
                float a = skey[idx], c = skey[ixj];
                bool asc = ((idx & k) == 0);
                bool sw = asc ? (a > c) : (a < c);
                if (sw) {
                    skey[idx] = c; skey[ixj] = a;
                    int ta = sidx[idx]; sidx[idx] = sidx[ixj]; sidx[ixj] = ta;
                }
            }
            __syncthreads();
        }
    }

    const float M = skey[1023];
    const float* hwb = hw + (size_t)b * (NNODE * 16);
    float Lf[17], Lg[17];
#pragma unroll
    for (int c = 0; c < 17; c++) { Lf[c] = 0.f; Lg[c] = 0.f; }

    const int p0 = tid * 4;
    // pass 1: local sums of 4 consecutive sorted positions
    for (int e = 0; e < 4; e++) {
        int pos = p0 + e;
        float key = skey[pos]; int j = sidx[pos];
        float f = __expf(key - M);
        float g = __expf(0.2f * (key - M));
        const float4* hj = (const float4*)(hwb + (size_t)j * 16);
        accum17(Lf, f, hj);
        accum17(Lg, g, hj);
    }

    const int lane = tid & 63, wv = tid >> 6;
    // wave inclusive scan
#pragma unroll
    for (int s = 1; s < 64; s <<= 1) {
#pragma unroll
        for (int c = 0; c < 17; c++) {
            float of = __shfl_up(Lf[c], s);
            float og = __shfl_up(Lg[c], s);
            if (lane >= s) { Lf[c] += of; Lg[c] += og; }
        }
    }
    if (lane == 63) {
#pragma unroll
        for (int c = 0; c < 17; c++) { wsum[wv][c] = Lf[c]; wsum[wv][17 + c] = Lg[c]; }
    }
    // convert to exclusive
#pragma unroll
    for (int c = 0; c < 17; c++) {
        float ef = __shfl_up(Lf[c], 1);
        float eg = __shfl_up(Lg[c], 1);
        Lf[c] = (lane == 0) ? 0.f : ef;
        Lg[c] = (lane == 0) ? 0.f : eg;
    }
    __syncthreads();
    // add totals of preceding waves
#pragma unroll
    for (int c = 0; c < 17; c++) {
        float bf = 0.f, bg = 0.f;
        for (int w2 = 0; w2 < wv; w2++) { bf += wsum[w2][c]; bg += wsum[w2][17 + c]; }
        Lf[c] += bf; Lg[c] += bg;
    }

    float* pfB = Pf + (size_t)b * (1025 * 20);
    float* pgB = Pg + (size_t)b * (1025 * 20);
    float* skB = skeys + b * NNODE;
    // pass 2: emit exclusive prefixes, then accumulate own elements
    for (int e = 0; e < 4; e++) {
        int pos = p0 + e;
        float key = skey[pos]; int j = sidx[pos];
        skB[pos] = key;
        store17(pfB + (size_t)pos * 20, Lf);
        store17(pgB + (size_t)pos * 20, Lg);
        float f = __expf(key - M);
        float g = __expf(0.2f * (key - M));
        const float4* hj = (const float4*)(hwb + (size_t)j * 16);
        accum17(Lf, f, hj);
        accum17(Lg, g, hj);
    }
    if (tid == 255) {   // grand totals -> row 1024
        store17(pfB + (size_t)1024 * 20, Lf);
        store17(pgB + (size_t)1024 * 20, Lg);
    }
}

// ---------------------------------------------------------------------------
// Per row i: binary search threshold, combine prefix rows, duplicated self-loop,
// divide, block-reduce sum over i -> atomicAdd into pooled[b][16].
__global__ __launch_bounds__(256) void attn_apply_kernel(
    const float* __restrict__ skeys, const float* __restrict__ s_src,
    const float* __restrict__ s_dst, const float* __restrict__ hw,
    const float* __restrict__ Pf, const float* __restrict__ Pg,
    float* __restrict__ pooled)
{
    __shared__ float sk[1024];
    __shared__ float red[256 * 16];
    const int tid = threadIdx.x, b = blockIdx.y;
    const int i = blockIdx.x * 256 + tid;

    const float* skB = skeys + b * NNODE;
    for (int t = tid; t < 1024; t += 256) sk[t] = skB[t];
    __syncthreads();

    const float M = sk[1023];
    const float sdi = s_dst[b * NNODE + i];
    const float eM = sdi + M;
    const float m_i = (eM >= 0.f) ? eM : 0.2f * eM;
    const float th = -sdi;

    int lo = 0, hi = 1024;
    while (lo < hi) { int mid = (lo + hi) >> 1; if (sk[mid] < th) lo = mid + 1; else hi = mid; }

    const float A  = __expf(eM - m_i);
    const float Bc = __expf(0.2f * eM - m_i);
    const float* pfB = Pf + (size_t)b * (1025 * 20);
    const float* pgB = Pg + (size_t)b * (1025 * 20);
    const float* pfT = pfB + (size_t)1024 * 20;
    const float* pf0 = pfB + (size_t)lo * 20;
    const float* pg0 = pgB + (size_t)lo * 20;

    float acc[17];
#pragma unroll
    for (int c = 0; c < 17; c++) acc[c] = A * (pfT[c] - pf0[c]) + Bc * pg0[c];

    // duplicated self-loop
    const float ssi = s_src[b * NNODE + i];
    float e2 = sdi + ssi;
    float el = (e2 >= 0.f) ? e2 : 0.2f * e2;
    float wii = __expf(el - m_i);
    const float* hi8 = hw + ((size_t)b * NNODE + i) * 16;
#pragma unroll
    for (int c = 0; c < 16; c++) acc[c] += wii * hi8[c];
    acc[16] += wii;

#pragma unroll
    for (int c = 0; c < 16; c++) red[tid * 16 + c] = acc[c] / acc[16];
    __syncthreads();
    for (int s = 128; s > 0; s >>= 1) {
        if (tid < s) {
#pragma unroll
            for (int c = 0; c < 16; c++) red[tid * 16 + c] += red[(tid + s) * 16 + c];
        }
        __syncthreads();
    }
    if (tid < 16) atomicAdd(pooled + b * 16 + tid, red[tid]);
}

// ---------------------------------------------------------------------------
__global__ void init_kernel(float* __restrict__ pooled)
{
    int idx = blockIdx.x * 256 + threadIdx.x;
    if (idx < BATCH * 16) pooled[idx] = 0.0f;
}

__global__ void final_kernel(
    const float* __restrict__ pooled, const float* __restrict__ gat_b,
    const float* __restrict__ fc_w, const float* __restrict__ fc_b,
    float* __restrict__ out)
{
    int b = threadIdx.x;
    if (b >= BATCH) return;
    float o0 = fc_b[0], o1 = fc_b[1];
#pragma unroll
    for (int d = 0; d < 16; d++) {
        float pv = pooled[b * 16 + d] * (1.0f / 1024.0f) + gat_b[d];
        o0 += pv * fc_w[d];
        o1 += pv * fc_w[16 + d];
    }
    out[2 * b] = o0;
    out[2 * b + 1] = o1;
}

// ---------------------------------------------------------------------------
extern "C" void kernel_launch(void* const* d_in, const int* in_sizes, int n_in,
                              void* d_out, int out_size, void* d_ws, size_t ws_size,
                              hipStream_t stream)
{
    (void)in_sizes; (void)n_in; (void)out_size; (void)ws_size;
    const float* x       = (const float*)d_in[0];
    const float* conv1_w = (const float*)d_in[1];
    const float* conv1_b = (const float*)d_in[2];
    const float* conv2_w = (const float*)d_in[3];
    const float* conv2_b = (const float*)d_in[4];
    const float* gat_w   = (const float*)d_in[5];
    const float* att_src = (const float*)d_in[6];
    const float* att_dst = (const float*)d_in[7];
    const float* gat_b   = (const float*)d_in[8];
    const float* fc_w    = (const float*)d_in[9];
    const float* fc_b    = (const float*)d_in[10];
    float* out = (float*)d_out;

    char* ws = (char*)d_ws;
    float* h1    = (float*)(ws + OFF_H1);
    float* h2    = (float*)(ws + OFF_H2);
    float* hw    = (float*)(ws + OFF_HW);
    float* ssrc  = (float*)(ws + OFF_SSRC);
    float* sdst  = (float*)(ws + OFF_SDST);
    float* pool  = (float*)(ws + OFF_POOL);
    float* skeys = (float*)(ws + OFF_SK);
    float* Pf    = (float*)(ws + OFF_PF);   // overlays h1 (h1 dead by then)
    float* Pg    = (float*)(ws + OFF_PG);   // overlays h1

    hipLaunchKernelGGL(init_kernel, dim3(8), dim3(256), 0, stream, pool);
    hipLaunchKernelGGL(conv1_kernel, dim3(P1 / 256, BATCH), dim3(256), 0, stream,
                       x, conv1_w, conv1_b, h1);
    hipLaunchKernelGGL(conv2_kernel, dim3(P2 / 128, BATCH), dim3(256), 0, stream,
                       h1, conv2_w, conv2_b, h2);
    hipLaunchKernelGGL(gat_hw_kernel, dim3(NNODE / 256, BATCH), dim3(256), 0, stream,
                       h2, gat_w, att_src, att_dst, hw, ssrc, sdst);
    hipLaunchKernelGGL(attn_prefix_kernel, dim3(BATCH), dim3(256), 0, stream,
                       ssrc, hw, Pf, Pg, skeys);
    hipLaunchKernelGGL(attn_apply_kernel, dim3(NNODE / 256, BATCH), dim3(256), 0, stream,
                       skeys, ssrc, sdst, hw, Pf, Pg, pool);
    hipLaunchKernelGGL(final_kernel, dim3(1), dim3(128), 0, stream,
                       pool, gat_b, fc_w, fc_b, out);
}

// Round 2
// 287.955 us; speedup vs baseline: 1.0584x; 1.0584x over previous
//
#include <hip/hip_runtime.h>
#include <cstddef>

// Problem dims
#define BATCH 128
#define T1 4096
#define P1 2048
#define T2 2048
#define P2 1024
#define NNODE 1024

// Workspace layout (bytes). Regions overlay dead buffers:
//  - Pf/Pg overlay h1 (dead after conv2)
//  - sidx overlays h2 (dead after gat_hw; rank runs after gat_hw)
//  - w1_t/w2_t overlay hw (dead until gat_hw; convs run before gat_hw)
#define OFF_H1   ((size_t)0)
#define OFF_PF   ((size_t)0)
#define OFF_PG   ((size_t)16777216)
#define OFF_H2   ((size_t)33554432)
#define OFF_SIDX ((size_t)33554432)
#define OFF_HW   ((size_t)67108864)
#define OFF_WT1  ((size_t)67108864)
#define OFF_WT2  ((size_t)67125248)
#define OFF_SSRC ((size_t)75497472)
#define OFF_SDST ((size_t)76021760)
#define OFF_POOL ((size_t)76546048)
#define OFF_SK   ((size_t)76554240)
// total ws used: 77,078,528 bytes (same as round 1)

// ---------------------------------------------------------------------------
// Weight transpose: w1 [32][17][5] -> w1_t [17][5][32]; w2 [64][32][5] -> w2_t [32][5][64]
__global__ void transpose_w_kernel(const float* __restrict__ w1, const float* __restrict__ w2,
                                   float* __restrict__ w1_t, float* __restrict__ w2_t)
{
    int idx = blockIdx.x * 256 + threadIdx.x;
    if (idx < 32 * 17 * 5) {
        int k = idx % 5, c = (idx / 5) % 17, o = idx / 85;
        w1_t[(c * 5 + k) * 32 + o] = w1[idx];
    }
    if (idx < 64 * 32 * 5) {
        int k = idx % 5, c = (idx / 5) % 32, o = idx / 160;
        w2_t[(c * 5 + k) * 64 + o] = w2[idx];
    }
}

// ---------------------------------------------------------------------------
// conv1 (17->32, k=5, pad=2) + relu + maxpool2. x:[128,17,4096] -> h1:[128,32,2048]
// Block 256 thr = 4 ocGroups(8 oc) x 64 posGroups(2 pooled). Grid (16,128).
__global__ __launch_bounds__(256, 4) void conv1_kernel(
    const float* __restrict__ x, const float* __restrict__ w_t,
    const float* __restrict__ bias, float* __restrict__ out)
{
    __shared__ __align__(16) float sx[17 * 260];
    __shared__ __align__(16) float sw[17 * 5 * 32];
    __shared__ float sb[32];
    const int tid = threadIdx.x;
    const int b = blockIdx.y;
    const int pool0 = blockIdx.x * 128;

    {
        const float4* src = (const float4*)w_t;
        float4* dst = (float4*)sw;
        for (int i = tid; i < 680; i += 256) dst[i] = src[i];
    }
    if (tid < 32) sb[tid] = bias[tid];
    const float* xb = x + (size_t)b * (17 * T1);
    const int tstart = 2 * pool0 - 2;
    for (int idx = tid; idx < 17 * 260; idx += 256) {
        int c = idx / 260, tt = idx - c * 260;
        int t = tstart + tt;
        sx[c * 260 + tt] = (t >= 0 && t < T1) ? xb[c * T1 + t] : 0.0f;
    }
    __syncthreads();

    const int posg = tid & 63;
    const int ocg  = tid >> 6;
    float acc[4][8];
#pragma unroll
    for (int e = 0; e < 4; e++)
#pragma unroll
        for (int o = 0; o < 8; o++) acc[e][o] = 0.f;

    for (int c = 0; c < 17; c++) {
        float4 xa = *(const float4*)&sx[c * 260 + 4 * posg];
        float4 xc = *(const float4*)&sx[c * 260 + 4 * posg + 4];
        float xv[8] = {xa.x, xa.y, xa.z, xa.w, xc.x, xc.y, xc.z, xc.w};
#pragma unroll
        for (int k = 0; k < 5; k++) {
            const float4* wp = (const float4*)&sw[(c * 5 + k) * 32 + ocg * 8];
            float4 w0 = wp[0], w1 = wp[1];
            float wv[8] = {w0.x, w0.y, w0.z, w0.w, w1.x, w1.y, w1.z, w1.w};
#pragma unroll
            for (int e = 0; e < 4; e++) {
                float xs = xv[e + k];
#pragma unroll
                for (int o = 0; o < 8; o++) acc[e][o] += xs * wv[o];
            }
        }
    }
    float* ob = out + (size_t)b * (32 * P1) + pool0 + 2 * posg;
#pragma unroll
    for (int o = 0; o < 8; o++) {
        int oc = ocg * 8 + o;
        float bo = sb[oc];
        float m0 = fmaxf(fmaxf(acc[0][o], acc[1][o]) + bo, 0.f);
        float m1 = fmaxf(fmaxf(acc[2][o], acc[3][o]) + bo, 0.f);
        *(float2*)&ob[(size_t)oc * P1] = make_float2(m0, m1);
    }
}

// ---------------------------------------------------------------------------
// conv2 (32->64, k=5, pad=2) + relu + maxpool2. h1 -> h2:[128,64,1024]
// Block 256 thr = 8 ocGroups(8 oc) x 32 posGroups(4 pooled). Grid (8,128).
// Weights read from global (L1-resident pre-transposed table), only x in LDS.
__global__ __launch_bounds__(256, 3) void conv2_kernel(
    const float* __restrict__ h1, const float* __restrict__ w_t,
    const float* __restrict__ bias, float* __restrict__ out)
{
    __shared__ __align__(16) float sx[32 * 260];
    __shared__ float sb[64];
    const int tid = threadIdx.x;
    const int b = blockIdx.y;
    const int pool0 = blockIdx.x * 128;
    if (tid < 64) sb[tid] = bias[tid];
    const float* xb = h1 + (size_t)b * (32 * T2);
    const int tstart = 2 * pool0 - 2;
    for (int idx = tid; idx < 32 * 260; idx += 256) {
        int c = idx / 260, tt = idx - c * 260;
        int t = tstart + tt;
        sx[c * 260 + tt] = (t >= 0 && t < T2) ? xb[c * T2 + t] : 0.0f;
    }
    __syncthreads();

    const int posg = tid & 31;
    const int ocg  = tid >> 5;
    float acc[8][8];
#pragma unroll
    for (int e = 0; e < 8; e++)
#pragma unroll
        for (int o = 0; o < 8; o++) acc[e][o] = 0.f;

    const float* wb = w_t + ocg * 8;
    for (int c = 0; c < 32; c++) {
        const float4* xp = (const float4*)&sx[c * 260 + 8 * posg];
        float4 x0 = xp[0], x1 = xp[1], x2 = xp[2];
        float xv[12] = {x0.x, x0.y, x0.z, x0.w, x1.x, x1.y, x1.z, x1.w,
                        x2.x, x2.y, x2.z, x2.w};
#pragma unroll
        for (int k = 0; k < 5; k++) {
            const float4* wp = (const float4*)(wb + (c * 5 + k) * 64);
            float4 w0 = wp[0], w1 = wp[1];
            float wv[8] = {w0.x, w0.y, w0.z, w0.w, w1.x, w1.y, w1.z, w1.w};
#pragma unroll
            for (int e = 0; e < 8; e++) {
                float xs = xv[e + k];
#pragma unroll
                for (int o = 0; o < 8; o++) acc[e][o] += xs * wv[o];
            }
        }
    }
    float* ob = out + (size_t)b * (64 * P2) + pool0 + 4 * posg;
#pragma unroll
    for (int o = 0; o < 8; o++) {
        int oc = ocg * 8 + o;
        float bo = sb[oc];
        float4 r;
        r.x = fmaxf(fmaxf(acc[0][o], acc[1][o]) + bo, 0.f);
        r.y = fmaxf(fmaxf(acc[2][o], acc[3][o]) + bo, 0.f);
        r.z = fmaxf(fmaxf(acc[4][o], acc[5][o]) + bo, 0.f);
        r.w = fmaxf(fmaxf(acc[6][o], acc[7][o]) + bo, 0.f);
        *(float4*)&ob[(size_t)oc * P2] = r;
    }
}

// ---------------------------------------------------------------------------
// GAT projection. 2 nodes/thread to halve broadcast LDS reads. Grid (2,128).
__global__ __launch_bounds__(256) void gat_hw_kernel(
    const float* __restrict__ h2, const float* __restrict__ gat_w,
    const float* __restrict__ att_src, const float* __restrict__ att_dst,
    float* __restrict__ hw, float* __restrict__ s_src, float* __restrict__ s_dst)
{
    __shared__ __align__(16) float sgw[64 * 16];
    __shared__ float sas[16], sad[16];
    const int tid = threadIdx.x, b = blockIdx.y;
    const int n0 = blockIdx.x * 512 + tid;
    const int n1 = n0 + 256;
    for (int idx = tid; idx < 1024; idx += 256) {
        int o = idx & 15, d = idx >> 4;
        sgw[d * 16 + o] = gat_w[o * 64 + d];
    }
    if (tid < 16) { sas[tid] = att_src[tid]; sad[tid] = att_dst[tid]; }
    __syncthreads();

    const float* hb = h2 + (size_t)b * (64 * NNODE);
    float4 a0[4], a1[4];
#pragma unroll
    for (int q = 0; q < 4; q++) {
        a0[q] = make_float4(0.f, 0.f, 0.f, 0.f);
        a1[q] = make_float4(0.f, 0.f, 0.f, 0.f);
    }
    for (int d = 0; d < 64; d++) {
        float hv0 = hb[(size_t)d * NNODE + n0];
        float hv1 = hb[(size_t)d * NNODE + n1];
        const float4* wq = (const float4*)&sgw[d * 16];
#pragma unroll
        for (int q = 0; q < 4; q++) {
            float4 wv = wq[q];
            a0[q].x += hv0 * wv.x; a0[q].y += hv0 * wv.y;
            a0[q].z += hv0 * wv.z; a0[q].w += hv0 * wv.w;
            a1[q].x += hv1 * wv.x; a1[q].y += hv1 * wv.y;
            a1[q].z += hv1 * wv.z; a1[q].w += hv1 * wv.w;
        }
    }
    float* f0 = (float*)a0;
    float* f1 = (float*)a1;
    float ss0 = 0.f, sd0 = 0.f, ss1 = 0.f, sd1 = 0.f;
#pragma unroll
    for (int c = 0; c < 16; c++) {
        ss0 += f0[c] * sas[c]; sd0 += f0[c] * sad[c];
        ss1 += f1[c] * sas[c]; sd1 += f1[c] * sad[c];
    }
    float4* hp0 = (float4*)(hw + ((size_t)b * NNODE + n0) * 16);
    float4* hp1 = (float4*)(hw + ((size_t)b * NNODE + n1) * 16);
#pragma unroll
    for (int q = 0; q < 4; q++) { hp0[q] = a0[q]; hp1[q] = a1[q]; }
    s_src[b * NNODE + n0] = ss0; s_dst[b * NNODE + n0] = sd0;
    s_src[b * NNODE + n1] = ss1; s_dst[b * NNODE + n1] = sd1;
}

// ---------------------------------------------------------------------------
// Rank-count "sort": rank_j = #{u: key_u < key_j or (== and u<j)}; scatter.
// Grid (2, 128): block handles 512 nodes, 2 per thread.
__global__ __launch_bounds__(256) void rank_kernel(
    const float* __restrict__ s_src, float* __restrict__ skeys, int* __restrict__ sidx)
{
    __shared__ __align__(16) float sk[1024];
    const int tid = threadIdx.x, b = blockIdx.y;
    const float* ssb = s_src + b * NNODE;
    for (int t = tid; t < 1024; t += 256) sk[t] = ssb[t];
    __syncthreads();
    const int j0 = blockIdx.x * 512 + tid;
    const int j1 = j0 + 256;
    const float k0 = sk[j0], k1 = sk[j1];
    int r0 = 0, r1 = 0;
    const float4* skv = (const float4*)sk;
    for (int u4 = 0; u4 < 256; u4++) {
        float4 kv = skv[u4];
        int u = u4 * 4;
        r0 += (kv.x < k0) || (kv.x == k0 && (u + 0) < j0);
        r0 += (kv.y < k0) || (kv.y == k0 && (u + 1) < j0);
        r0 += (kv.z < k0) || (kv.z == k0 && (u + 2) < j0);
        r0 += (kv.w < k0) || (kv.w == k0 && (u + 3) < j0);
        r1 += (kv.x < k1) || (kv.x == k1 && (u + 0) < j1);
        r1 += (kv.y < k1) || (kv.y == k1 && (u + 1) < j1);
        r1 += (kv.z < k1) || (kv.z == k1 && (u + 2) < j1);
        r1 += (kv.w < k1) || (kv.w == k1 && (u + 3) < j1);
    }
    skeys[b * NNODE + r0] = k0; sidx[b * NNODE + r0] = j0;
    skeys[b * NNODE + r1] = k1; sidx[b * NNODE + r1] = j1;
}

// ---------------------------------------------------------------------------
__device__ __forceinline__ void accum17(float* L, float wgt, const float4* hj)
{
    float4 h0 = hj[0], h1 = hj[1], h2 = hj[2], h3 = hj[3];
    L[0]  += wgt * h0.x; L[1]  += wgt * h0.y; L[2]  += wgt * h0.z; L[3]  += wgt * h0.w;
    L[4]  += wgt * h1.x; L[5]  += wgt * h1.y; L[6]  += wgt * h1.z; L[7]  += wgt * h1.w;
    L[8]  += wgt * h2.x; L[9]  += wgt * h2.y; L[10] += wgt * h2.z; L[11] += wgt * h2.w;
    L[12] += wgt * h3.x; L[13] += wgt * h3.y; L[14] += wgt * h3.z; L[15] += wgt * h3.w;
    L[16] += wgt;
}

__device__ __forceinline__ void store17(float* dst, const float* L)
{
    *(float4*)(dst + 0)  = make_float4(L[0],  L[1],  L[2],  L[3]);
    *(float4*)(dst + 4)  = make_float4(L[4],  L[5],  L[6],  L[7]);
    *(float4*)(dst + 8)  = make_float4(L[8],  L[9],  L[10], L[11]);
    *(float4*)(dst + 12) = make_float4(L[12], L[13], L[14], L[15]);
    dst[16] = L[16];
}

// Prefix sums over sorted order (no sort here; rank_kernel did it).
// Grid (128). Rows padded to 20 floats; row 1024 = grand totals (Pf only used).
__global__ __launch_bounds__(256) void attn_prefix_kernel(
    const float* __restrict__ skeys, const int* __restrict__ sidx,
    const float* __restrict__ hw, float* __restrict__ Pf, float* __restrict__ Pg)
{
    __shared__ float wsum[4][34];
    const int tid = threadIdx.x, b = blockIdx.x;
    const float* skB = skeys + b * NNODE;
    const int* siB = sidx + b * NNODE;
    const float M = skB[1023];
    const float* hwb = hw + (size_t)b * (NNODE * 16);

    float4 kv = ((const float4*)skB)[tid];
    int4 jv = ((const int4*)siB)[tid];
    float keys[4] = {kv.x, kv.y, kv.z, kv.w};
    int js[4] = {jv.x, jv.y, jv.z, jv.w};

    float Lf[17], Lg[17];
#pragma unroll
    for (int c = 0; c < 17; c++) { Lf[c] = 0.f; Lg[c] = 0.f; }

#pragma unroll
    for (int e = 0; e < 4; e++) {
        float f = __expf(keys[e] - M);
        float g = __expf(0.2f * (keys[e] - M));
        const float4* hj = (const float4*)(hwb + (size_t)js[e] * 16);
        accum17(Lf, f, hj);
        accum17(Lg, g, hj);
    }

    const int lane = tid & 63, wv = tid >> 6;
#pragma unroll
    for (int s = 1; s < 64; s <<= 1) {
#pragma unroll
        for (int c = 0; c < 17; c++) {
            float of = __shfl_up(Lf[c], s);
            float og = __shfl_up(Lg[c], s);
            if (lane >= s) { Lf[c] += of; Lg[c] += og; }
        }
    }
    if (lane == 63) {
#pragma unroll
        for (int c = 0; c < 17; c++) { wsum[wv][c] = Lf[c]; wsum[wv][17 + c] = Lg[c]; }
    }
#pragma unroll
    for (int c = 0; c < 17; c++) {
        float ef = __shfl_up(Lf[c], 1);
        float eg = __shfl_up(Lg[c], 1);
        Lf[c] = (lane == 0) ? 0.f : ef;
        Lg[c] = (lane == 0) ? 0.f : eg;
    }
    __syncthreads();
#pragma unroll
    for (int c = 0; c < 17; c++) {
        float bf = 0.f, bg = 0.f;
        for (int w2 = 0; w2 < wv; w2++) { bf += wsum[w2][c]; bg += wsum[w2][17 + c]; }
        Lf[c] += bf; Lg[c] += bg;
    }

    float* pfB = Pf + (size_t)b * (1025 * 20);
    float* pgB = Pg + (size_t)b * (1025 * 20);
#pragma unroll
    for (int e = 0; e < 4; e++) {
        int pos = tid * 4 + e;
        store17(pfB + (size_t)pos * 20, Lf);
        store17(pgB + (size_t)pos * 20, Lg);
        float f = __expf(keys[e] - M);
        float g = __expf(0.2f * (keys[e] - M));
        const float4* hj = (const float4*)(hwb + (size_t)js[e] * 16);
        accum17(Lf, f, hj);
        accum17(Lg, g, hj);
    }
    if (tid == 255) {
        store17(pfB + (size_t)1024 * 20, Lf);
        store17(pgB + (size_t)1024 * 20, Lg);
    }
}

// ---------------------------------------------------------------------------
// Per row i: binary search + prefix lookup + duplicated self-loop + reduce.
__global__ __launch_bounds__(256) void attn_apply_kernel(
    const float* __restrict__ skeys, const float* __restrict__ s_src,
    const float* __restrict__ s_dst, const float* __restrict__ hw,
    const float* __restrict__ Pf, const float* __restrict__ Pg,
    float* __restrict__ pooled)
{
    __shared__ float sk[1024];
    __shared__ float spf[17];
    __shared__ float red[256 * 17];
    const int tid = threadIdx.x, b = blockIdx.y;
    const int i = blockIdx.x * 256 + tid;

    const float* skB = skeys + b * NNODE;
    const float* pfB = Pf + (size_t)b * (1025 * 20);
    const float* pgB = Pg + (size_t)b * (1025 * 20);
    for (int t = tid; t < 1024; t += 256) sk[t] = skB[t];
    if (tid < 17) spf[tid] = pfB[(size_t)1024 * 20 + tid];
    __syncthreads();

    const float M = sk[1023];
    const float sdi = s_dst[b * NNODE + i];
    const float eM = sdi + M;
    const float m_i = (eM >= 0.f) ? eM : 0.2f * eM;
    const float th = -sdi;

    int lo = 0, hi = 1024;
    while (lo < hi) { int mid = (lo + hi) >> 1; if (sk[mid] < th) lo = mid + 1; else hi = mid; }

    const float A  = __expf(eM - m_i);
    const float Bc = __expf(0.2f * eM - m_i);
    const float* pf0 = pfB + (size_t)lo * 20;
    const float* pg0 = pgB + (size_t)lo * 20;

    float acc[17];
#pragma unroll
    for (int c = 0; c < 17; c++) acc[c] = A * (spf[c] - pf0[c]) + Bc * pg0[c];

    const float ssi = s_src[b * NNODE + i];
    float e2 = sdi + ssi;
    float el = (e2 >= 0.f) ? e2 : 0.2f * e2;
    float wii = __expf(el - m_i);
    const float* hi8 = hw + ((size_t)b * NNODE + i) * 16;
#pragma unroll
    for (int c = 0; c < 16; c++) acc[c] += wii * hi8[c];
    acc[16] += wii;

    float inv = 1.0f / acc[16];
#pragma unroll
    for (int c = 0; c < 16; c++) red[tid * 17 + c] = acc[c] * inv;
    __syncthreads();
    for (int s = 128; s > 0; s >>= 1) {
        if (tid < s) {
#pragma unroll
            for (int c = 0; c < 16; c++) red[tid * 17 + c] += red[(tid + s) * 17 + c];
        }
        __syncthreads();
    }
    if (tid < 16) atomicAdd(pooled + b * 16 + tid, red[tid]);
}

// ---------------------------------------------------------------------------
__global__ void init_kernel(float* __restrict__ pooled)
{
    int idx = blockIdx.x * 256 + threadIdx.x;
    if (idx < BATCH * 16) pooled[idx] = 0.0f;
}

__global__ void final_kernel(
    const float* __restrict__ pooled, const float* __restrict__ gat_b,
    const float* __restrict__ fc_w, const float* __restrict__ fc_b,
    float* __restrict__ out)
{
    int b = threadIdx.x;
    if (b >= BATCH) return;
    float o0 = fc_b[0], o1 = fc_b[1];
#pragma unroll
    for (int d = 0; d < 16; d++) {
        float pv = pooled[b * 16 + d] * (1.0f / 1024.0f) + gat_b[d];
        o0 += pv * fc_w[d];
        o1 += pv * fc_w[16 + d];
    }
    out[2 * b] = o0;
    out[2 * b + 1] = o1;
}

// ---------------------------------------------------------------------------
extern "C" void kernel_launch(void* const* d_in, const int* in_sizes, int n_in,
                              void* d_out, int out_size, void* d_ws, size_t ws_size,
                              hipStream_t stream)
{
    (void)in_sizes; (void)n_in; (void)out_size; (void)ws_size;
    const float* x       = (const float*)d_in[0];
    const float* conv1_w = (const float*)d_in[1];
    const float* conv1_b = (const float*)d_in[2];
    const float* conv2_w = (const float*)d_in[3];
    const float* conv2_b = (const float*)d_in[4];
    const float* gat_w   = (const float*)d_in[5];
    const float* att_src = (const float*)d_in[6];
    const float* att_dst = (const float*)d_in[7];
    const float* gat_b   = (const float*)d_in[8];
    const float* fc_w    = (const float*)d_in[9];
    const float* fc_b    = (const float*)d_in[10];
    float* out = (float*)d_out;

    char* ws = (char*)d_ws;
    float* h1    = (float*)(ws + OFF_H1);
    float* h2    = (float*)(ws + OFF_H2);
    float* hw    = (float*)(ws + OFF_HW);
    float* w1t   = (float*)(ws + OFF_WT1);
    float* w2t   = (float*)(ws + OFF_WT2);
    float* ssrc  = (float*)(ws + OFF_SSRC);
    float* sdst  = (float*)(ws + OFF_SDST);
    float* pool  = (float*)(ws + OFF_POOL);
    float* skeys = (float*)(ws + OFF_SK);
    int*   sidx  = (int*)(ws + OFF_SIDX);
    float* Pf    = (float*)(ws + OFF_PF);
    float* Pg    = (float*)(ws + OFF_PG);

    hipLaunchKernelGGL(transpose_w_kernel, dim3(40), dim3(256), 0, stream,
                       conv1_w, conv2_w, w1t, w2t);
    hipLaunchKernelGGL(init_kernel, dim3(8), dim3(256), 0, stream, pool);
    hipLaunchKernelGGL(conv1_kernel, dim3(16, BATCH), dim3(256), 0, stream,
                       x, w1t, conv1_b, h1);
    hipLaunchKernelGGL(conv2_kernel, dim3(8, BATCH), dim3(256), 0, stream,
                       h1, w2t, conv2_b, h2);
    hipLaunchKernelGGL(gat_hw_kernel, dim3(2, BATCH), dim3(256), 0, stream,
                       h2, gat_w, att_src, att_dst, hw, ssrc, sdst);
    hipLaunchKernelGGL(rank_kernel, dim3(2, BATCH), dim3(256), 0, stream,
                       ssrc, skeys, sidx);
    hipLaunchKernelGGL(attn_prefix_kernel, dim3(BATCH), dim3(256), 0, stream,
                       skeys, sidx, hw, Pf, Pg);
    hipLaunchKernelGGL(attn_apply_kernel, dim3(4, BATCH), dim3(256), 0, stream,
                       skeys, ssrc, sdst, hw, Pf, Pg, pool);
    hipLaunchKernelGGL(final_kernel, dim3(1), dim3(128), 0, stream,
                       pool, gat_b, fc_w, fc_b, out);
}

// Round 3
// 270.984 us; speedup vs baseline: 1.1247x; 1.0626x over previous
//
#include <hip/hip_runtime.h>
#include <cstddef>

// Problem dims
#define BATCH 128
#define T1 4096
#define P1 2048
#define T2 2048
#define P2 1024
#define NNODE 1024

// Workspace layout (bytes). Overlays:
//  - Pf/Pg overlay h1 (h1 dead after conv2; Pf/Pg written after)
//  - weight tables overlay skeys region (skeys written only by rank_prefix,
//    which runs after every consumer of the weights)
#define OFF_H1   ((size_t)0)
#define OFF_PF   ((size_t)0)
#define OFF_PG   ((size_t)16777216)
#define OFF_H2   ((size_t)33554432)
#define OFF_HW   ((size_t)67108864)
#define OFF_SSRC ((size_t)75497472)
#define OFF_SDST ((size_t)76021760)
#define OFF_POOL ((size_t)76546048)
#define OFF_SK   ((size_t)76554240)
#define OFF_WT1  ((size_t)76554240)   // 2720 floats, overlays skeys
#define OFF_WT2  ((size_t)76565120)   // 10240 floats
#define OFF_GWT  ((size_t)76606080)   // 1024 floats
// total ws used: 77,078,528 bytes (unchanged)

// ---------------------------------------------------------------------------
// Prep: weight transposes + pooled zero-init.
// w1 [32][17][5] -> w1t [17*5][32]; w2 [64][32][5] -> w2t [32*5][64];
// gat_w [16][64] -> gwt [64][16]; pooled[2048] = 0.
__global__ void prep_kernel(const float* __restrict__ w1, const float* __restrict__ w2,
                            const float* __restrict__ gw,
                            float* __restrict__ w1t, float* __restrict__ w2t,
                            float* __restrict__ gwt, float* __restrict__ pooled)
{
    int idx = blockIdx.x * 256 + threadIdx.x;
    if (idx < 32 * 17 * 5) {
        int k = idx % 5, c = (idx / 5) % 17, o = idx / 85;
        w1t[(c * 5 + k) * 32 + o] = w1[idx];
    }
    if (idx < 64 * 32 * 5) {
        int k = idx % 5, c = (idx / 5) % 32, o = idx / 160;
        w2t[(c * 5 + k) * 64 + o] = w2[idx];
    }
    if (idx < 1024) {
        int d = idx >> 4, o = idx & 15;
        gwt[idx] = gw[o * 64 + d];
    }
    if (idx < BATCH * 16) pooled[idx] = 0.0f;
}

// ---------------------------------------------------------------------------
// conv1 (17->32, k=5, pad=2) + relu + maxpool2. x:[128,17,4096] -> h1:[128,32,2048]
// Block 256 = 4 waves; wave wv owns oc [wv*8, wv*8+8); lane owns 4 prepool pos.
// Weights via wave-uniform loads -> SGPR (scalar pipe), x via LDS. Grid (16,128).
__global__ __launch_bounds__(256, 6) void conv1_kernel(
    const float* __restrict__ x, const float* __restrict__ w_t,
    const float* __restrict__ bias, float* __restrict__ out)
{
    __shared__ __align__(16) float sx[17 * 260];
    const int tid = threadIdx.x;
    const int b = blockIdx.y;
    const int pool0 = blockIdx.x * 128;
    const int lane = tid & 63;
    const int wv = __builtin_amdgcn_readfirstlane(tid >> 6);

    const float* xb = x + (size_t)b * (17 * T1);
    const int tstart = 2 * pool0 - 2;
    for (int idx = tid; idx < 17 * 260; idx += 256) {
        int c = idx / 260, tt = idx - c * 260;
        int t = tstart + tt;
        sx[idx] = (t >= 0 && t < T1) ? xb[c * T1 + t] : 0.0f;
    }
    __syncthreads();

    float acc[4][8];
#pragma unroll
    for (int e = 0; e < 4; e++)
#pragma unroll
        for (int o = 0; o < 8; o++) acc[e][o] = 0.f;

    const float* wb = w_t + wv * 8;
#pragma unroll 1
    for (int c = 0; c < 17; c++) {
        float4 xa = *(const float4*)&sx[c * 260 + 4 * lane];
        float4 xc = *(const float4*)&sx[c * 260 + 4 * lane + 4];
        float xv[8] = {xa.x, xa.y, xa.z, xa.w, xc.x, xc.y, xc.z, xc.w};
#pragma unroll
        for (int k = 0; k < 5; k++) {
            const float* wp = wb + (c * 5 + k) * 32;      // wave-uniform -> s_load
            float4 w0 = *(const float4*)(wp);
            float4 w1 = *(const float4*)(wp + 4);
            float wr[8] = {w0.x, w0.y, w0.z, w0.w, w1.x, w1.y, w1.z, w1.w};
#pragma unroll
            for (int e = 0; e < 4; e++) {
                float xs = xv[e + k];
#pragma unroll
                for (int o = 0; o < 8; o++) acc[e][o] += xs * wr[o];
            }
        }
    }
    float* ob = out + (size_t)b * (32 * P1) + pool0 + 2 * lane;
#pragma unroll
    for (int o = 0; o < 8; o++) {
        int oc = wv * 8 + o;
        float bo = bias[oc];                               // uniform -> s_load
        float m0 = fmaxf(fmaxf(acc[0][o], acc[1][o]) + bo, 0.f);
        float m1 = fmaxf(fmaxf(acc[2][o], acc[3][o]) + bo, 0.f);
        *(float2*)&ob[(size_t)oc * P1] = make_float2(m0, m1);
    }
}

// ---------------------------------------------------------------------------
// conv2 (32->64, k=5, pad=2) + relu + maxpool2. h1 -> h2:[128,64,1024]
// Block 256 = 4 waves; wave wv owns oc [wv*16, wv*16+16); lane owns 4 prepool.
// Grid (8,128).
__global__ __launch_bounds__(256, 4) void conv2_kernel(
    const float* __restrict__ h1, const float* __restrict__ w_t,
    const float* __restrict__ bias, float* __restrict__ out)
{
    __shared__ __align__(16) float sx[32 * 260];
    const int tid = threadIdx.x;
    const int b = blockIdx.y;
    const int pool0 = blockIdx.x * 128;
    const int lane = tid & 63;
    const int wv = __builtin_amdgcn_readfirstlane(tid >> 6);

    const float* xb = h1 + (size_t)b * (32 * T2);
    const int tstart = 2 * pool0 - 2;
    for (int idx = tid; idx < 32 * 260; idx += 256) {
        int c = idx / 260, tt = idx - c * 260;
        int t = tstart + tt;
        sx[idx] = (t >= 0 && t < T2) ? xb[c * T2 + t] : 0.0f;
    }
    __syncthreads();

    float acc[4][16];
#pragma unroll
    for (int e = 0; e < 4; e++)
#pragma unroll
        for (int o = 0; o < 16; o++) acc[e][o] = 0.f;

    const float* wb = w_t + wv * 16;
#pragma unroll 1
    for (int c = 0; c < 32; c++) {
        float4 xa = *(const float4*)&sx[c * 260 + 4 * lane];
        float4 xc = *(const float4*)&sx[c * 260 + 4 * lane + 4];
        float xv[8] = {xa.x, xa.y, xa.z, xa.w, xc.x, xc.y, xc.z, xc.w};
#pragma unroll
        for (int k = 0; k < 5; k++) {
            const float* wp = wb + (c * 5 + k) * 64;      // wave-uniform -> s_load
            float4 w0 = *(const float4*)(wp);
            float4 w1 = *(const float4*)(wp + 4);
            float4 w2 = *(const float4*)(wp + 8);
            float4 w3 = *(const float4*)(wp + 12);
            float wr[16] = {w0.x, w0.y, w0.z, w0.w, w1.x, w1.y, w1.z, w1.w,
                            w2.x, w2.y, w2.z, w2.w, w3.x, w3.y, w3.z, w3.w};
#pragma unroll
            for (int e = 0; e < 4; e++) {
                float xs = xv[e + k];
#pragma unroll
                for (int o = 0; o < 16; o++) acc[e][o] += xs * wr[o];
            }
        }
    }
    float* ob = out + (size_t)b * (64 * P2) + pool0 + 2 * lane;
#pragma unroll
    for (int o = 0; o < 16; o++) {
        int oc = wv * 16 + o;
        float bo = bias[oc];
        float m0 = fmaxf(fmaxf(acc[0][o], acc[1][o]) + bo, 0.f);
        float m1 = fmaxf(fmaxf(acc[2][o], acc[3][o]) + bo, 0.f);
        *(float2*)&ob[(size_t)oc * P2] = make_float2(m0, m1);
    }
}

// ---------------------------------------------------------------------------
// GAT projection, 1 node/thread, weights row-wise via uniform s_load (no LDS).
// Grid (4,128).
__global__ __launch_bounds__(256, 4) void gat_hw_kernel(
    const float* __restrict__ h2, const float* __restrict__ gwt,
    const float* __restrict__ att_src, const float* __restrict__ att_dst,
    float* __restrict__ hw, float* __restrict__ s_src, float* __restrict__ s_dst)
{
    const int tid = threadIdx.x, b = blockIdx.y;
    const int n = blockIdx.x * 256 + tid;

    const float* hb = h2 + (size_t)b * (64 * NNODE) + n;
    float acc[16];
#pragma unroll
    for (int o = 0; o < 16; o++) acc[o] = 0.f;

#pragma unroll 4
    for (int d = 0; d < 64; d++) {
        float hv = hb[(size_t)d * NNODE];
        const float* wp = gwt + d * 16;                   // uniform -> s_load
        float4 w0 = *(const float4*)(wp);
        float4 w1 = *(const float4*)(wp + 4);
        float4 w2 = *(const float4*)(wp + 8);
        float4 w3 = *(const float4*)(wp + 12);
        acc[0]  += hv * w0.x; acc[1]  += hv * w0.y; acc[2]  += hv * w0.z; acc[3]  += hv * w0.w;
        acc[4]  += hv * w1.x; acc[5]  += hv * w1.y; acc[6]  += hv * w1.z; acc[7]  += hv * w1.w;
        acc[8]  += hv * w2.x; acc[9]  += hv * w2.y; acc[10] += hv * w2.z; acc[11] += hv * w2.w;
        acc[12] += hv * w3.x; acc[13] += hv * w3.y; acc[14] += hv * w3.z; acc[15] += hv * w3.w;
    }
    float ss = 0.f, sd = 0.f;
#pragma unroll
    for (int c = 0; c < 16; c++) {
        ss += acc[c] * att_src[c];                        // uniform -> s_load
        sd += acc[c] * att_dst[c];
    }
    float4* hp = (float4*)(hw + ((size_t)b * NNODE + n) * 16);
    hp[0] = make_float4(acc[0], acc[1], acc[2], acc[3]);
    hp[1] = make_float4(acc[4], acc[5], acc[6], acc[7]);
    hp[2] = make_float4(acc[8], acc[9], acc[10], acc[11]);
    hp[3] = make_float4(acc[12], acc[13], acc[14], acc[15]);
    s_src[b * NNODE + n] = ss;
    s_dst[b * NNODE + n] = sd;
}

// ---------------------------------------------------------------------------
__device__ __forceinline__ void accum17(float* L, float wgt, const float4* hj)
{
    float4 h0 = hj[0], h1 = hj[1], h2 = hj[2], h3 = hj[3];
    L[0]  += wgt * h0.x; L[1]  += wgt * h0.y; L[2]  += wgt * h0.z; L[3]  += wgt * h0.w;
    L[4]  += wgt * h1.x; L[5]  += wgt * h1.y; L[6]  += wgt * h1.z; L[7]  += wgt * h1.w;
    L[8]  += wgt * h2.x; L[9]  += wgt * h2.y; L[10] += wgt * h2.z; L[11] += wgt * h2.w;
    L[12] += wgt * h3.x; L[13] += wgt * h3.y; L[14] += wgt * h3.z; L[15] += wgt * h3.w;
    L[16] += wgt;
}

__device__ __forceinline__ void store17(float* dst, const float* L)
{
    *(float4*)(dst + 0)  = make_float4(L[0],  L[1],  L[2],  L[3]);
    *(float4*)(dst + 4)  = make_float4(L[4],  L[5],  L[6],  L[7]);
    *(float4*)(dst + 8)  = make_float4(L[8],  L[9],  L[10], L[11]);
    *(float4*)(dst + 12) = make_float4(L[12], L[13], L[14], L[15]);
    dst[16] = L[16];
}

// ---------------------------------------------------------------------------
// Merged rank (stable sort via rank-count) + exclusive prefix sums.
// One block (512 thr) per batch; sorted keys/idx never leave LDS.
// Pf/Pg rows padded to 20 floats; row 1024 = grand totals.
__global__ __launch_bounds__(512) void rank_prefix_kernel(
    const float* __restrict__ s_src, const float* __restrict__ hw,
    float* __restrict__ Pf, float* __restrict__ Pg, float* __restrict__ skeys)
{
    __shared__ __align__(16) float sk[1024];
    __shared__ __align__(16) float sks[1024];
    __shared__ int sis[1024];
    __shared__ float wsum[8][34];
    const int tid = threadIdx.x, b = blockIdx.x;

    const float* ssb = s_src + b * NNODE;
    for (int t = tid; t < 1024; t += 512) sk[t] = ssb[t];
    __syncthreads();

    const int j0 = 2 * tid, j1 = 2 * tid + 1;
    const float k0 = sk[j0], k1 = sk[j1];
    int r0 = 0, r1 = 0;
    const float4* skv = (const float4*)sk;
    for (int u4 = 0; u4 < 256; u4++) {
        float4 kv = skv[u4];
        int u = u4 * 4;
        r0 += (kv.x < k0) || (kv.x == k0 && (u + 0) < j0);
        r0 += (kv.y < k0) || (kv.y == k0 && (u + 1) < j0);
        r0 += (kv.z < k0) || (kv.z == k0 && (u + 2) < j0);
        r0 += (kv.w < k0) || (kv.w == k0 && (u + 3) < j0);
        r1 += (kv.x < k1) || (kv.x == k1 && (u + 0) < j1);
        r1 += (kv.y < k1) || (kv.y == k1 && (u + 1) < j1);
        r1 += (kv.z < k1) || (kv.z == k1 && (u + 2) < j1);
        r1 += (kv.w < k1) || (kv.w == k1 && (u + 3) < j1);
    }
    sks[r0] = k0; sis[r0] = j0;
    sks[r1] = k1; sis[r1] = j1;
    __syncthreads();

    const float M = sks[1023];
    const float* hwb = hw + (size_t)b * (NNODE * 16);
    const float key0 = sks[j0], key1 = sks[j1];
    const int i0 = sis[j0], i1 = sis[j1];
    const float f0 = __expf(key0 - M), g0 = __expf(0.2f * (key0 - M));
    const float f1 = __expf(key1 - M), g1 = __expf(0.2f * (key1 - M));
    const float4* hj0 = (const float4*)(hwb + (size_t)i0 * 16);
    const float4* hj1 = (const float4*)(hwb + (size_t)i1 * 16);

    float Lf[17], Lg[17];
#pragma unroll
    for (int c = 0; c < 17; c++) { Lf[c] = 0.f; Lg[c] = 0.f; }
    accum17(Lf, f0, hj0); accum17(Lg, g0, hj0);
    accum17(Lf, f1, hj1); accum17(Lg, g1, hj1);

    const int lane = tid & 63, wv = tid >> 6;
#pragma unroll
    for (int s = 1; s < 64; s <<= 1) {
#pragma unroll
        for (int c = 0; c < 17; c++) {
            float of = __shfl_up(Lf[c], s);
            float og = __shfl_up(Lg[c], s);
            if (lane >= s) { Lf[c] += of; Lg[c] += og; }
        }
    }
    if (lane == 63) {
#pragma unroll
        for (int c = 0; c < 17; c++) { wsum[wv][c] = Lf[c]; wsum[wv][17 + c] = Lg[c]; }
    }
#pragma unroll
    for (int c = 0; c < 17; c++) {
        float ef = __shfl_up(Lf[c], 1);
        float eg = __shfl_up(Lg[c], 1);
        Lf[c] = (lane == 0) ? 0.f : ef;
        Lg[c] = (lane == 0) ? 0.f : eg;
    }
    __syncthreads();
#pragma unroll
    for (int c = 0; c < 17; c++) {
        float bf = 0.f, bg = 0.f;
        for (int w2 = 0; w2 < wv; w2++) { bf += wsum[w2][c]; bg += wsum[w2][17 + c]; }
        Lf[c] += bf; Lg[c] += bg;
    }

    float* pfB = Pf + (size_t)b * (1025 * 20);
    float* pgB = Pg + (size_t)b * (1025 * 20);
    float* skB = skeys + b * NNODE;

    store17(pfB + (size_t)j0 * 20, Lf);
    store17(pgB + (size_t)j0 * 20, Lg);
    skB[j0] = key0;
    accum17(Lf, f0, hj0); accum17(Lg, g0, hj0);
    store17(pfB + (size_t)j1 * 20, Lf);
    store17(pgB + (size_t)j1 * 20, Lg);
    skB[j1] = key1;
    accum17(Lf, f1, hj1); accum17(Lg, g1, hj1);
    if (tid == 511) {
        store17(pfB + (size_t)1024 * 20, Lf);
        store17(pgB + (size_t)1024 * 20, Lg);
    }
}

// ---------------------------------------------------------------------------
// Per row i: binary search + prefix lookup + duplicated self-loop + shuffle
// reduce -> atomicAdd pooled. Grid (4,128).
__global__ __launch_bounds__(256) void attn_apply_kernel(
    const float* __restrict__ skeys, const float* __restrict__ s_src,
    const float* __restrict__ s_dst, const float* __restrict__ hw,
    const float* __restrict__ Pf, const float* __restrict__ Pg,
    float* __restrict__ pooled)
{
    __shared__ __align__(16) float sk[1024];
    __shared__ float spf[17];
    __shared__ float sred[4][16];
    const int tid = threadIdx.x, b = blockIdx.y;
    const int i = blockIdx.x * 256 + tid;
    const int lane = tid & 63, wv = tid >> 6;

    const float* skB = skeys + b * NNODE;
    const float* pfB = Pf + (size_t)b * (1025 * 20);
    const float* pgB = Pg + (size_t)b * (1025 * 20);
    for (int t = tid; t < 1024; t += 256) sk[t] = skB[t];
    if (tid < 17) spf[tid] = pfB[(size_t)1024 * 20 + tid];
    __syncthreads();

    const float M = sk[1023];
    const float sdi = s_dst[b * NNODE + i];
    const float eM = sdi + M;
    const float m_i = (eM >= 0.f) ? eM : 0.2f * eM;
    const float th = -sdi;

    int lo = 0, hi = 1024;
    while (lo < hi) { int mid = (lo + hi) >> 1; if (sk[mid] < th) lo = mid + 1; else hi = mid; }

    const float A  = __expf(eM - m_i);
    const float Bc = __expf(0.2f * eM - m_i);
    const float* pf0 = pfB + (size_t)lo * 20;
    const float* pg0 = pgB + (size_t)lo * 20;

    float acc[17];
#pragma unroll
    for (int c = 0; c < 17; c++) acc[c] = A * (spf[c] - pf0[c]) + Bc * pg0[c];

    const float ssi = s_src[b * NNODE + i];
    float e2 = sdi + ssi;
    float el = (e2 >= 0.f) ? e2 : 0.2f * e2;
    float wii = __expf(el - m_i);
    const float* hi8 = hw + ((size_t)b * NNODE + i) * 16;
#pragma unroll
    for (int c = 0; c < 16; c++) acc[c] += wii * hi8[c];
    acc[16] += wii;

    float inv = 1.0f / acc[16];
    float r[16];
#pragma unroll
    for (int c = 0; c < 16; c++) r[c] = acc[c] * inv;
#pragma unroll
    for (int s = 32; s > 0; s >>= 1) {
#pragma unroll
        for (int c = 0; c < 16; c++) r[c] += __shfl_down(r[c], s);
    }
    if (lane == 0) {
#pragma unroll
        for (int c = 0; c < 16; c++) sred[wv][c] = r[c];
    }
    __syncthreads();
    if (tid < 16) {
        float t = sred[0][tid] + sred[1][tid] + sred[2][tid] + sred[3][tid];
        atomicAdd(pooled + b * 16 + tid, t);
    }
}

// ---------------------------------------------------------------------------
__global__ void final_kernel(
    const float* __restrict__ pooled, const float* __restrict__ gat_b,
    const float* __restrict__ fc_w, const float* __restrict__ fc_b,
    float* __restrict__ out)
{
    int b = threadIdx.x;
    if (b >= BATCH) return;
    float o0 = fc_b[0], o1 = fc_b[1];
#pragma unroll
    for (int d = 0; d < 16; d++) {
        float pv = pooled[b * 16 + d] * (1.0f / 1024.0f) + gat_b[d];
        o0 += pv * fc_w[d];
        o1 += pv * fc_w[16 + d];
    }
    out[2 * b] = o0;
    out[2 * b + 1] = o1;
}

// ---------------------------------------------------------------------------
extern "C" void kernel_launch(void* const* d_in, const int* in_sizes, int n_in,
                              void* d_out, int out_size, void* d_ws, size_t ws_size,
                              hipStream_t stream)
{
    (void)in_sizes; (void)n_in; (void)out_size; (void)ws_size;
    const float* x       = (const float*)d_in[0];
    const float* conv1_w = (const float*)d_in[1];
    const float* conv1_b = (const float*)d_in[2];
    const float* conv2_w = (const float*)d_in[3];
    const float* conv2_b = (const float*)d_in[4];
    const float* gat_w   = (const float*)d_in[5];
    const float* att_src = (const float*)d_in[6];
    const float* att_dst = (const float*)d_in[7];
    const float* gat_b   = (const float*)d_in[8];
    const float* fc_w    = (const float*)d_in[9];
    const float* fc_b    = (const float*)d_in[10];
    float* out = (float*)d_out;

    char* ws = (char*)d_ws;
    float* h1    = (float*)(ws + OFF_H1);
    float* h2    = (float*)(ws + OFF_H2);
    float* hw    = (float*)(ws + OFF_HW);
    float* w1t   = (float*)(ws + OFF_WT1);
    float* w2t   = (float*)(ws + OFF_WT2);
    float* gwt   = (float*)(ws + OFF_GWT);
    float* ssrc  = (float*)(ws + OFF_SSRC);
    float* sdst  = (float*)(ws + OFF_SDST);
    float* pool  = (float*)(ws + OFF_POOL);
    float* skeys = (float*)(ws + OFF_SK);
    float* Pf    = (float*)(ws + OFF_PF);
    float* Pg    = (float*)(ws + OFF_PG);

    hipLaunchKernelGGL(prep_kernel, dim3(40), dim3(256), 0, stream,
                       conv1_w, conv2_w, gat_w, w1t, w2t, gwt, pool);
    hipLaunchKernelGGL(conv1_kernel, dim3(16, BATCH), dim3(256), 0, stream,
                       x, w1t, conv1_b, h1);
    hipLaunchKernelGGL(conv2_kernel, dim3(8, BATCH), dim3(256), 0, stream,
                       h1, w2t, conv2_b, h2);
    hipLaunchKernelGGL(gat_hw_kernel, dim3(4, BATCH), dim3(256), 0, stream,
                       h2, gwt, att_src, att_dst, hw, ssrc, sdst);
    hipLaunchKernelGGL(rank_prefix_kernel, dim3(BATCH), dim3(512), 0, stream,
                       ssrc, hw, Pf, Pg, skeys);
    hipLaunchKernelGGL(attn_apply_kernel, dim3(4, BATCH), dim3(256), 0, stream,
                       skeys, ssrc, sdst, hw, Pf, Pg, pool);
    hipLaunchKernelGGL(final_kernel, dim3(1), dim3(128), 0, stream,
                       pool, gat_b, fc_w, fc_b, out);
}